// Round 5
// baseline (116.011 us; speedup 1.0000x reference)
//
#include <hip/hip_runtime.h>

// SpatialLoss: x [64,16,256,256] f32 -> scalar
// loss = sum_{(i,j) in [-2,2]^2 \ (0,0)} (1/sqrt(i^2+j^2)) * sum((shifted diff)^2) / 64 / 256 / 256
//
// R4: product form. sum (x[p+d]-x[p])^2 over all 24 offsets =
//     2 * sum_q W(q) x[q]^2 - 4 * sum_{half-space d} (1/w_d) sum_p x[p] x[p+d],
//     W(q) = sum of 1/w over q's in-bounds 24-neighborhood. Zero-padded windows
//     -> no edge masks in cross terms; border-row weight fixes outside hot loop.
// R5: single-pass — last-done block performs the final reduction (device-scope
//     fence + counter in d_ws, counter zeroed per call via hipMemsetAsync node).
//     Saves the 2nd dispatch's launch/gap (~4 us). Final sum order fixed ->
//     bit-deterministic output.

#define RR 256
#define CCOLS 256
#define NBLOCKS 2048

// g(j) = sum_{i=-2..2,(i,j)!=(0,0)} 1/sqrt(i*i+j*j)
#define G1 3.30864075337301081f   // j=+-1
#define G2 2.10153397218646371f   // j=+-2
// missing row-weights: row0/row255 (i in {-1,-2} absent)
#define M00 1.5f
#define M01 1.15432037668650540f  // 1/sqrt(2)+1/sqrt(5)
#define M02 0.80076698609323170f  // 1/sqrt(5)+1/sqrt(8)
// row1/row254 (i=-2 absent)
#define M10 0.5f
#define M11 0.44721359549995794f  // 1/sqrt(5)
#define M12 0.35355339059327376f  // 1/sqrt(8)

#define RS2 0.70710678118654752f  // 1/sqrt(2)
#define RS5 0.44721359549995794f  // 1/sqrt(5)
#define RS8 0.35355339059327376f  // 1/sqrt(8)

// Load 8-float window (cols 4*sc-2 .. 4*sc+5) with ZERO padding at plane edges.
__device__ __forceinline__ void load_row8z(const float* __restrict__ rowp, int sc, float (&W)[8]) {
    const int c0 = sc << 2;
    const int lo = (sc == 0)  ? 0 : (c0 - 2);
    const int hi = (sc == 63) ? (CCOLS - 2) : (c0 + 4);
    float2 l2 = *reinterpret_cast<const float2*>(rowp + lo);
    float4 q  = *reinterpret_cast<const float4*>(rowp + c0);
    float2 h2 = *reinterpret_cast<const float2*>(rowp + hi);
    const bool e0 = (sc == 0), e1 = (sc == 63);
    W[0] = e0 ? 0.f : l2.x;  W[1] = e0 ? 0.f : l2.y;
    W[2] = q.x; W[3] = q.y; W[4] = q.z; W[5] = q.w;
    W[6] = e1 ? 0.f : h2.x;  W[7] = e1 ? 0.f : h2.y;
}

// A=row r, B=row r+1, C=row r+2; center k is A[k+2], neighbor (k,j)=W[k+2+j].
__device__ __forceinline__ void pacc4(const float (&A)[8], const float (&B)[8], const float (&C)[8],
                                      float &s1, float &s2, float &s4, float &s5, float &s8,
                                      float (&Q)[4])
{
#pragma unroll
    for (int k = 0; k < 4; ++k) {
        const float v = A[k + 2];
        Q[k] = fmaf(v, v, Q[k]);
        s1 = fmaf(v, A[k + 3] + B[k + 2], s1);
        s2 = fmaf(v, B[k + 1] + B[k + 3], s2);
        s4 = fmaf(v, A[k + 4] + C[k + 2], s4);
        s5 = fmaf(v, (B[k] + B[k + 4]) + (C[k + 1] + C[k + 3]), s5);
        s8 = fmaf(v, C[k] + C[k + 4], s8);
    }
}

__global__ __launch_bounds__(256) void spatial_loss_fused(const float* __restrict__ x,
                                                          float* __restrict__ partial,
                                                          unsigned int* __restrict__ counter,
                                                          float* __restrict__ out)
{
    const int b   = blockIdx.x;          // 0..2047: plane b>>1, half b&1
    const int tid = threadIdx.x;
    const int sr  = tid >> 6;            // wave id: one wave = one full 256-col row
    const int sc  = tid & 63;            // 4 cols per lane
    const float* plane = x + (size_t)(b >> 1) * (RR * CCOLS);
    const int r0 = ((b & 1) << 7) + (sr << 5);   // 0,32,...,224
    const int cbase = sc << 2;

    float W0[8], W1[8], W2[8], W3[8];
    load_row8z(plane + (size_t)(r0    ) * CCOLS, sc, W0);
    load_row8z(plane + (size_t)(r0 + 1) * CCOLS, sc, W1);
    load_row8z(plane + (size_t)(r0 + 2) * CCOLS, sc, W2);

    // per-lane interior-row squared-term weights W(c) = 3 + a*G1 + b*G2
    float Wk[4];
#pragma unroll
    for (int k = 0; k < 4; ++k) {
        const int c  = cbase + k;
        const float a  = ((c >= 1) ? 1.f : 0.f) + ((c <= 254) ? 1.f : 0.f);
        const float bb = ((c >= 2) ? 1.f : 0.f) + ((c <= 253) ? 1.f : 0.f);
        Wk[k] = 3.0f + a * G1 + bb * G2;
    }

    float s1 = 0.f, s2 = 0.f, s4 = 0.f, s5 = 0.f, s8 = 0.f;
    float Q[4] = {0.f, 0.f, 0.f, 0.f};
    float bacc = 0.f;   // border-row weight corrections (subtracted)

    if (r0 == 0) {      // rows 0 and 1 centers are in W0, W1
#pragma unroll
        for (int k = 0; k < 4; ++k) {
            const int c  = cbase + k;
            const float a  = ((c >= 1) ? 1.f : 0.f) + ((c <= 254) ? 1.f : 0.f);
            const float bb = ((c >= 2) ? 1.f : 0.f) + ((c <= 253) ? 1.f : 0.f);
            const float cw0 = M00 + a * M01 + bb * M02;
            const float cw1 = M10 + a * M11 + bb * M12;
            const float v0 = W0[k + 2], v1 = W1[k + 2];
            bacc = fmaf(cw0, v0 * v0, bacc);
            bacc = fmaf(cw1, v1 * v1, bacc);
        }
    }

    // i = 0..27: rotation; prefetch row r0+i+3 (rows r0+3..r0+30, always <= 254).
    const float* pn = plane + (size_t)(r0 + 3) * CCOLS;
#pragma unroll 1
    for (int g = 0; g < 7; ++g) {
        load_row8z(pn,             sc, W3); pacc4(W0, W1, W2, s1, s2, s4, s5, s8, Q);
        load_row8z(pn +     CCOLS, sc, W0); pacc4(W1, W2, W3, s1, s2, s4, s5, s8, Q);
        load_row8z(pn + 2 * CCOLS, sc, W1); pacc4(W2, W3, W0, s1, s2, s4, s5, s8, Q);
        load_row8z(pn + 3 * CCOLS, sc, W2); pacc4(W3, W0, W1, s1, s2, s4, s5, s8, Q);
        pn += 4 * CCOLS;
    }

    // tail i = 28..31; rows r0+32, r0+33 zero-padded for the last strip.
    const bool last = (r0 == 224);
    load_row8z(pn, sc, W3);                                   // row r0+31
    pacc4(W0, W1, W2, s1, s2, s4, s5, s8, Q);                 // i=28
    if (last) {
#pragma unroll
        for (int q = 0; q < 8; ++q) W0[q] = 0.f;
    } else {
        load_row8z(plane + (size_t)(r0 + 32) * CCOLS, sc, W0);
    }
    pacc4(W1, W2, W3, s1, s2, s4, s5, s8, Q);                 // i=29
    if (last) {
#pragma unroll
        for (int q = 0; q < 8; ++q) W1[q] = 0.f;
    } else {
        load_row8z(plane + (size_t)(r0 + 33) * CCOLS, sc, W1);
    }
    pacc4(W2, W3, W0, s1, s2, s4, s5, s8, Q);                 // i=30
    pacc4(W3, W0, W1, s1, s2, s4, s5, s8, Q);                 // i=31

    if (last) {         // rows 254 (W2) and 255 (W3) corrections
#pragma unroll
        for (int k = 0; k < 4; ++k) {
            const int c  = cbase + k;
            const float a  = ((c >= 1) ? 1.f : 0.f) + ((c <= 254) ? 1.f : 0.f);
            const float bb = ((c >= 2) ? 1.f : 0.f) + ((c <= 253) ? 1.f : 0.f);
            const float cw254 = M10 + a * M11 + bb * M12;
            const float cw255 = M00 + a * M01 + bb * M02;
            const float v4 = W2[k + 2], v5 = W3[k + 2];
            bacc = fmaf(cw254, v4 * v4, bacc);
            bacc = fmaf(cw255, v5 * v5, bacc);
        }
    }

    const float sq = fmaf(Wk[0], Q[0], fmaf(Wk[1], Q[1], fmaf(Wk[2], Q[2], Wk[3] * Q[3]))) - bacc;
    const float cross = s1 + RS2 * s2 + 0.5f * s4 + RS5 * s5 + RS8 * s8;
    float t = 2.0f * sq - 4.0f * cross;

    // wave (64) reduce, then block reduce
    #pragma unroll
    for (int off = 32; off; off >>= 1) t += __shfl_down(t, off, 64);
    __shared__ float wsum[4];
    __shared__ int isLast;
    const int wave = tid >> 6, lane = tid & 63;
    if (lane == 0) wsum[wave] = t;
    __syncthreads();
    if (tid == 0) {
        partial[b] = wsum[0] + wsum[1] + wsum[2] + wsum[3];
        __threadfence();                                   // device-scope release
        unsigned int old = atomicAdd(counter, 1u);         // device-scope
        isLast = (old == NBLOCKS - 1) ? 1 : 0;
    }
    __syncthreads();

    if (isLast) {
        __threadfence();                                   // acquire side
        float s = 0.f;
#pragma unroll 2
        for (int q = 0; q < 8; ++q)
            s += __hip_atomic_load(&partial[tid + (q << 8)], __ATOMIC_RELAXED,
                                   __HIP_MEMORY_SCOPE_AGENT);
        #pragma unroll
        for (int off = 32; off; off >>= 1) s += __shfl_down(s, off, 64);
        if (lane == 0) wsum[wave] = s;
        __syncthreads();
        if (tid == 0)
            out[0] = (wsum[0] + wsum[1] + wsum[2] + wsum[3]) * (1.0f / 4194304.0f);
    }
}

extern "C" void kernel_launch(void* const* d_in, const int* in_sizes, int n_in,
                              void* d_out, int out_size, void* d_ws, size_t ws_size,
                              hipStream_t stream) {
    const float* x = (const float*)d_in[0];
    float* out     = (float*)d_out;
    float* partial = (float*)d_ws;                          // 2048 floats = 8 KB
    unsigned int* counter = (unsigned int*)((char*)d_ws + NBLOCKS * sizeof(float));
    hipMemsetAsync(counter, 0, sizeof(unsigned int), stream);   // graph-capturable node
    spatial_loss_fused<<<NBLOCKS, 256, 0, stream>>>(x, partial, counter, out);
}

// Round 8
// 46.847 us; speedup vs baseline: 2.4764x; 2.4764x over previous
//
#include <hip/hip_runtime.h>

// SpatialLoss: x [64,16,256,256] f32 -> scalar
// loss = sum_{(i,j) in [-2,2]^2 \ (0,0)} (1/sqrt(i^2+j^2)) * sum((shifted diff)^2) / 64 / 256 / 256
//
// R4: product form. sum over 24 offsets of (x[p+d]-x[p])^2 =
//     2*sum_q W(q) x[q]^2 - 4*sum_{half-space d} (1/w_d) sum_p x[p] x[p+d].
//     Zero-padded windows -> no edge masks; border-row fixes outside hot loop.
// R8: two-kernel structure restored (R5-R7 showed: no cheap fence-free
//     cross-XCD handoff exists; the dispatch boundary IS the cheap fence).
//     Inter-wave row halo now passed through LDS: each wave stores its
//     prologue W0/W1 windows; wave sr reads wave sr+1's as its tail rows.
//     Halo 6.25% -> 0.78% (only block-bottom wave fetches 2 global rows).

#define RR 256
#define CCOLS 256
#define NBLOCKS 2048

// g(j) = sum_{i=-2..2,(i,j)!=(0,0)} 1/sqrt(i*i+j*j)
#define G1 3.30864075337301081f   // j=+-1
#define G2 2.10153397218646371f   // j=+-2
// missing row-weights: row0/row255 (i in {-1,-2} absent)
#define M00 1.5f
#define M01 1.15432037668650540f  // 1/sqrt(2)+1/sqrt(5)
#define M02 0.80076698609323170f  // 1/sqrt(5)+1/sqrt(8)
// row1/row254 (i=-2 absent)
#define M10 0.5f
#define M11 0.44721359549995794f  // 1/sqrt(5)
#define M12 0.35355339059327376f  // 1/sqrt(8)

#define RS2 0.70710678118654752f  // 1/sqrt(2)
#define RS5 0.44721359549995794f  // 1/sqrt(5)
#define RS8 0.35355339059327376f  // 1/sqrt(8)

// Load 8-float window (cols 4*sc-2 .. 4*sc+5) with ZERO padding at plane edges.
__device__ __forceinline__ void load_row8z(const float* __restrict__ rowp, int sc, float (&W)[8]) {
    const int c0 = sc << 2;
    const int lo = (sc == 0)  ? 0 : (c0 - 2);
    const int hi = (sc == 63) ? (CCOLS - 2) : (c0 + 4);
    float2 l2 = *reinterpret_cast<const float2*>(rowp + lo);
    float4 q  = *reinterpret_cast<const float4*>(rowp + c0);
    float2 h2 = *reinterpret_cast<const float2*>(rowp + hi);
    const bool e0 = (sc == 0), e1 = (sc == 63);
    W[0] = e0 ? 0.f : l2.x;  W[1] = e0 ? 0.f : l2.y;
    W[2] = q.x; W[3] = q.y; W[4] = q.z; W[5] = q.w;
    W[6] = e1 ? 0.f : h2.x;  W[7] = e1 ? 0.f : h2.y;
}

// A=row r, B=row r+1, C=row r+2; center k is A[k+2], neighbor (k,j)=W[k+2+j].
__device__ __forceinline__ void pacc4(const float (&A)[8], const float (&B)[8], const float (&C)[8],
                                      float &s1, float &s2, float &s4, float &s5, float &s8,
                                      float (&Q)[4])
{
#pragma unroll
    for (int k = 0; k < 4; ++k) {
        const float v = A[k + 2];
        Q[k] = fmaf(v, v, Q[k]);
        s1 = fmaf(v, A[k + 3] + B[k + 2], s1);
        s2 = fmaf(v, B[k + 1] + B[k + 3], s2);
        s4 = fmaf(v, A[k + 4] + C[k + 2], s4);
        s5 = fmaf(v, (B[k] + B[k + 4]) + (C[k + 1] + C[k + 3]), s5);
        s8 = fmaf(v, C[k] + C[k + 4], s8);
    }
}

__global__ __launch_bounds__(256) void spatial_loss_partial(const float* __restrict__ x,
                                                            float* __restrict__ partial)
{
    const int b   = blockIdx.x;          // 0..2047: plane b>>1, half b&1
    const int tid = threadIdx.x;
    const int sr  = tid >> 6;            // wave id 0..3 (32 rows each)
    const int sc  = tid & 63;            // 4 cols per lane
    const float* plane = x + (size_t)(b >> 1) * (RR * CCOLS);
    const int half = b & 1;
    const int r0 = (half << 7) + (sr << 5);      // 0,32,...,224
    const int cbase = sc << 2;

    // inter-wave halo handoff: wave sr's prologue rows (r0, r0+1) in windowed
    // form are exactly what wave sr-1 needs as its tail rows (r0'+32, r0'+33).
    __shared__ float hx[4][2][64 * 8];   // 16 KB

    float W0[8], W1[8], W2[8], W3[8];
    load_row8z(plane + (size_t)(r0    ) * CCOLS, sc, W0);
    load_row8z(plane + (size_t)(r0 + 1) * CCOLS, sc, W1);
    load_row8z(plane + (size_t)(r0 + 2) * CCOLS, sc, W2);

#pragma unroll
    for (int q = 0; q < 8; ++q) { hx[sr][0][(sc << 3) + q] = W0[q]; hx[sr][1][(sc << 3) + q] = W1[q]; }
    __syncthreads();

    // per-lane interior-row squared-term weights W(c) = 3 + a*G1 + b*G2
    float Wk[4];
#pragma unroll
    for (int k = 0; k < 4; ++k) {
        const int c  = cbase + k;
        const float a  = ((c >= 1) ? 1.f : 0.f) + ((c <= 254) ? 1.f : 0.f);
        const float bb = ((c >= 2) ? 1.f : 0.f) + ((c <= 253) ? 1.f : 0.f);
        Wk[k] = 3.0f + a * G1 + bb * G2;
    }

    float s1 = 0.f, s2 = 0.f, s4 = 0.f, s5 = 0.f, s8 = 0.f;
    float Q[4] = {0.f, 0.f, 0.f, 0.f};
    float bacc = 0.f;   // border-row weight corrections (subtracted)

    if (r0 == 0) {      // rows 0 and 1 centers are in W0, W1
#pragma unroll
        for (int k = 0; k < 4; ++k) {
            const int c  = cbase + k;
            const float a  = ((c >= 1) ? 1.f : 0.f) + ((c <= 254) ? 1.f : 0.f);
            const float bb = ((c >= 2) ? 1.f : 0.f) + ((c <= 253) ? 1.f : 0.f);
            const float cw0 = M00 + a * M01 + bb * M02;
            const float cw1 = M10 + a * M11 + bb * M12;
            const float v0 = W0[k + 2], v1 = W1[k + 2];
            bacc = fmaf(cw0, v0 * v0, bacc);
            bacc = fmaf(cw1, v1 * v1, bacc);
        }
    }

    // i = 0..27: 7 groups of 4; prefetch row r0+i+3 (rows r0+3..r0+30, <= 254).
    const float* pn = plane + (size_t)(r0 + 3) * CCOLS;
#pragma unroll 1
    for (int g = 0; g < 7; ++g) {
        load_row8z(pn,             sc, W3); pacc4(W0, W1, W2, s1, s2, s4, s5, s8, Q);
        load_row8z(pn +     CCOLS, sc, W0); pacc4(W1, W2, W3, s1, s2, s4, s5, s8, Q);
        load_row8z(pn + 2 * CCOLS, sc, W1); pacc4(W2, W3, W0, s1, s2, s4, s5, s8, Q);
        load_row8z(pn + 3 * CCOLS, sc, W2); pacc4(W3, W0, W1, s1, s2, s4, s5, s8, Q);
        pn += 4 * CCOLS;
    }

    // tail i = 28..31. Buffers hold rows (r0+28, r0+29, r0+30); pn = row r0+31.
    // Rows r0+32, r0+33: LDS handoff for sr<3; block-bottom wave loads global
    // (half 0 -> rows 128,129) or zero-pads (half 1 -> plane bottom).
    const bool last = (r0 == 224);
    load_row8z(pn, sc, W3);                                   // row r0+31
    pacc4(W0, W1, W2, s1, s2, s4, s5, s8, Q);                 // i=28
    if (sr < 3) {
#pragma unroll
        for (int q = 0; q < 8; ++q) W0[q] = hx[sr + 1][0][(sc << 3) + q];
    } else if (half == 0) {
        load_row8z(plane + (size_t)128 * CCOLS, sc, W0);
    } else {
#pragma unroll
        for (int q = 0; q < 8; ++q) W0[q] = 0.f;
    }
    pacc4(W1, W2, W3, s1, s2, s4, s5, s8, Q);                 // i=29
    if (sr < 3) {
#pragma unroll
        for (int q = 0; q < 8; ++q) W1[q] = hx[sr + 1][1][(sc << 3) + q];
    } else if (half == 0) {
        load_row8z(plane + (size_t)129 * CCOLS, sc, W1);
    } else {
#pragma unroll
        for (int q = 0; q < 8; ++q) W1[q] = 0.f;
    }
    pacc4(W2, W3, W0, s1, s2, s4, s5, s8, Q);                 // i=30 (row r0+30)
    pacc4(W3, W0, W1, s1, s2, s4, s5, s8, Q);                 // i=31 (row r0+31)

    if (last) {         // rows 254 (W2 centers) and 255 (W3 centers) corrections
#pragma unroll
        for (int k = 0; k < 4; ++k) {
            const int c  = cbase + k;
            const float a  = ((c >= 1) ? 1.f : 0.f) + ((c <= 254) ? 1.f : 0.f);
            const float bb = ((c >= 2) ? 1.f : 0.f) + ((c <= 253) ? 1.f : 0.f);
            const float cw254 = M10 + a * M11 + bb * M12;
            const float cw255 = M00 + a * M01 + bb * M02;
            const float v4 = W2[k + 2], v5 = W3[k + 2];
            bacc = fmaf(cw254, v4 * v4, bacc);
            bacc = fmaf(cw255, v5 * v5, bacc);
        }
    }

    const float sq = fmaf(Wk[0], Q[0], fmaf(Wk[1], Q[1], fmaf(Wk[2], Q[2], Wk[3] * Q[3]))) - bacc;
    const float cross = s1 + RS2 * s2 + 0.5f * s4 + RS5 * s5 + RS8 * s8;
    float t = 2.0f * sq - 4.0f * cross;

    // wave (64) reduce, then block reduce
    #pragma unroll
    for (int off = 32; off; off >>= 1) t += __shfl_down(t, off, 64);
    __shared__ float wsum[4];
    const int wave = tid >> 6, lane = tid & 63;
    if (lane == 0) wsum[wave] = t;
    __syncthreads();
    if (tid == 0) partial[b] = wsum[0] + wsum[1] + wsum[2] + wsum[3];
}

__global__ __launch_bounds__(256) void reduce_partials(const float* __restrict__ partial,
                                                       float* __restrict__ out)
{
    const int tid = threadIdx.x;
    float s = 0.f;
    #pragma unroll
    for (int q = 0; q < 8; ++q) s += partial[tid + (q << 8)];
    #pragma unroll
    for (int off = 32; off; off >>= 1) s += __shfl_down(s, off, 64);
    __shared__ float wsum[4];
    if ((tid & 63) == 0) wsum[tid >> 6] = s;
    __syncthreads();
    if (tid == 0) out[0] = (wsum[0] + wsum[1] + wsum[2] + wsum[3]) * (1.0f / 4194304.0f);
}

extern "C" void kernel_launch(void* const* d_in, const int* in_sizes, int n_in,
                              void* d_out, int out_size, void* d_ws, size_t ws_size,
                              hipStream_t stream) {
    const float* x = (const float*)d_in[0];
    float* out     = (float*)d_out;
    float* partial = (float*)d_ws;   // 2048 floats = 8 KB
    spatial_loss_partial<<<NBLOCKS, 256, 0, stream>>>(x, partial);
    reduce_partials<<<1, 256, 0, stream>>>(partial, out);
}